// Round 1
// baseline (230.553 us; speedup 1.0000x reference)
//
#include <hip/hip_runtime.h>
#include <stdint.h>

#define B_   4
#define C_   64
#define HW_  9216
#define HS_  4
#define S_   2304
#define NBH  16
// 0.5 (softmax scale = 1/sqrt(head_size=4)) * log2(e), folded into Q at projection time
#define SCALE_LOG2E 0.72134752044448169136f

using f32x4 = __attribute__((ext_vector_type(4))) float;
using s16x8 = __attribute__((ext_vector_type(8))) short;   // 8 bf16 in 4 VGPRs

typedef const __attribute__((address_space(1))) void gbl_void;
typedef __attribute__((address_space(3))) void lds_void;

__device__ __forceinline__ uint16_t f2bf(float f) {
    uint32_t u = __builtin_bit_cast(uint32_t, f);
    uint32_t r = u + 0x7FFFu + ((u >> 16) & 1u);   // RNE
    return (uint16_t)(r >> 16);
}
__device__ __forceinline__ float bf2f(uint16_t h) {
    uint32_t u = ((uint32_t)h) << 16;
    return __builtin_bit_cast(float, u);
}

// ---------------------------------------------------------------------------
// Kernel 1: q/k/v projection (1x1 conv). grid=(576,3), block=64.
// mode 0: Q, scaled by 0.5*log2e, row-major [bh][s][c] bf16
// mode 1: K,                     row-major [bh][s][c] bf16
// mode 2: V, transposed          [bh][c][s] bf16 (coalesced column writes)
// ---------------------------------------------------------------------------
__global__ __launch_bounds__(64) void qkv_proj(
    const float* __restrict__ x,
    const float* __restrict__ Wq, const float* __restrict__ Wk, const float* __restrict__ Wv,
    const float* __restrict__ bq, const float* __restrict__ bk, const float* __restrict__ bv,
    uint16_t* __restrict__ Qo, uint16_t* __restrict__ Ko, uint16_t* __restrict__ Vo)
{
    const int mode = blockIdx.y;
    const float* W    = (mode == 0) ? Wq : (mode == 1) ? Wk : Wv;
    const float* bias = (mode == 0) ? bq : (mode == 1) ? bk : bv;

    const int pix = blockIdx.x * 64 + threadIdx.x;
    const int b  = pix / HW_;
    const int hw = pix % HW_;
    const int h  = hw / S_;
    const int s  = hw % S_;
    const int bh = b * HS_ + h;

    float xv[64];
    #pragma unroll
    for (int c = 0; c < 64; ++c)
        xv[c] = x[(size_t)(b * C_ + c) * HW_ + hw];   // coalesced across lanes

    if (mode == 2) {
        #pragma unroll 4
        for (int o = 0; o < 64; ++o) {
            float acc = bias[o];
            #pragma unroll
            for (int c = 0; c < 64; ++c) acc = fmaf(W[o * 64 + c], xv[c], acc);
            // V^T: [bh][c=o][s]; lanes write consecutive s -> coalesced
            Vo[((size_t)bh * 64 + o) * S_ + s] = f2bf(acc);
        }
    } else {
        const float scale = (mode == 0) ? SCALE_LOG2E : 1.0f;
        uint16_t* dst = ((mode == 0) ? Qo : Ko) + ((size_t)bh * S_ + s) * 64;
        #pragma unroll 4
        for (int op = 0; op < 32; ++op) {
            const int o = op * 2;
            float a0 = bias[o], a1 = bias[o + 1];
            #pragma unroll
            for (int c = 0; c < 64; ++c) {
                a0 = fmaf(W[o * 64 + c],       xv[c], a0);
                a1 = fmaf(W[(o + 1) * 64 + c], xv[c], a1);
            }
            a0 *= scale; a1 *= scale;
            uint32_t pk = (uint32_t)f2bf(a0) | ((uint32_t)f2bf(a1) << 16);
            ((uint32_t*)dst)[op] = pk;
        }
    }
}

// ---------------------------------------------------------------------------
// Kernel 2: flash attention. grid=(36,16), block=256 (4 waves x 16 queries).
// Layouts:  Q,K row-major [bh][s][c] bf16 ; V transposed [bh][c][s] bf16.
// K/V tiles staged via global_load_lds(16B) with XOR swizzle applied on the
// GLOBAL source address (LDS dest must stay linear): element (row, cb) lives
// at linear (row, cb ^ (row&7)). All fragment reads are ds_read_b128.
// A/B fragments use the SAME (lane,elem)->k mapping, so the MFMA dot product
// is correct for any internal HW k-permutation; only the verified C/D layout
// (col=lane&15, row=(lane>>4)*4+reg) is relied on for softmax/output.
// Output: [bh][t][c] bf16 == the reference's post-reshape (b,c',hw') buffer.
// ---------------------------------------------------------------------------
__global__ __launch_bounds__(256) void attn(
    const uint16_t* __restrict__ Qg, const uint16_t* __restrict__ Kg,
    const uint16_t* __restrict__ Vg, uint16_t* __restrict__ Og)
{
    const int bh   = blockIdx.y;
    const int qb   = blockIdx.x;
    const int tid  = threadIdx.x;
    const int wave = tid >> 6;
    const int lane = tid & 63;
    const int g    = lane >> 4;    // 0..3
    const int lr   = lane & 15;    // 0..15

    __shared__ alignas(16) uint16_t Klds[64 * 64];      // [key][c] swizzled
    __shared__ alignas(16) uint16_t Vlds[64 * 64];      // [c][s]   swizzled
    __shared__ alignas(16) uint16_t Plds[4][16 * 72];   // per-wave P, stride 72 (16B aligned rows)

    const uint16_t* Qb = Qg + (size_t)bh * S_ * 64;
    const uint16_t* Kb = Kg + (size_t)bh * S_ * 64;
    const uint16_t* Vb = Vg + (size_t)bh * 64 * S_;

    // Q A-fragments (held in registers for the whole block)
    const int q0 = qb * 64 + wave * 16;
    s16x8 qf[2];
    #pragma unroll
    for (int ks = 0; ks < 2; ++ks)
        qf[ks] = *(const s16x8*)(Qb + (size_t)(q0 + lr) * 64 + ks * 32 + g * 8);

    f32x4 oacc[4];
    float m_r[4], l_r[4];
    #pragma unroll
    for (int ct = 0; ct < 4; ++ct) oacc[ct] = (f32x4){0.f, 0.f, 0.f, 0.f};
    #pragma unroll
    for (int r = 0; r < 4; ++r) { m_r[r] = -1e30f; l_r[r] = 0.f; }

    for (int j = 0; j < 36; ++j) {
        // ---- stage K (8KB) and V (8KB); 2 chunks of 1KB per wave each ----
        #pragma unroll
        for (int call = 0; call < 2; ++call) {
            const int chunk = wave * 2 + call;        // 0..7
            const int slot  = chunk * 64 + lane;      // 0..511
            const int row   = slot >> 3;              // 0..63
            const int cbl   = slot & 7;
            const int cbs   = cbl ^ (row & 7);        // pre-swizzled source block
            const uint16_t* ksrc = Kb + ((size_t)(j * 64 + row) * 64 + cbs * 8);
            __builtin_amdgcn_global_load_lds((gbl_void*)ksrc,
                (lds_void*)(Klds + chunk * 512), 16, 0, 0);
            const uint16_t* vsrc = Vb + ((size_t)row * S_ + j * 64 + cbs * 8);
            __builtin_amdgcn_global_load_lds((gbl_void*)vsrc,
                (lds_void*)(Vlds + chunk * 512), 16, 0, 0);
        }
        asm volatile("s_waitcnt vmcnt(0)" ::: "memory");
        __syncthreads();

        // ---- S = Q * K^T  (logits already in exp2 domain via Q pre-scale) ----
        f32x4 sacc[4];
        #pragma unroll
        for (int kt = 0; kt < 4; ++kt) sacc[kt] = (f32x4){0.f, 0.f, 0.f, 0.f};
        #pragma unroll
        for (int ks = 0; ks < 2; ++ks) {
            #pragma unroll
            for (int kt = 0; kt < 4; ++kt) {
                const int key = kt * 16 + lr;
                const int cb  = (ks * 4 + g) ^ (key & 7);
                s16x8 kf = *(const s16x8*)(Klds + key * 64 + cb * 8);
                sacc[kt] = __builtin_amdgcn_mfma_f32_16x16x32_bf16(qf[ks], kf, sacc[kt], 0, 0, 0);
            }
        }

        // ---- online softmax (rows 4g+r, cols lr+16kt); 16-lane butterfly ----
        float tm[4];
        #pragma unroll
        for (int r = 0; r < 4; ++r)
            tm[r] = fmaxf(fmaxf(sacc[0][r], sacc[1][r]), fmaxf(sacc[2][r], sacc[3][r]));
        #pragma unroll
        for (int mask = 1; mask < 16; mask <<= 1) {
            #pragma unroll
            for (int r = 0; r < 4; ++r)
                tm[r] = fmaxf(tm[r], __shfl_xor(tm[r], mask, 64));
        }
        float sf[4];
        #pragma unroll
        for (int r = 0; r < 4; ++r) {
            const float mn = fmaxf(m_r[r], tm[r]);
            sf[r]  = exp2f(m_r[r] - mn);
            m_r[r] = mn;
            l_r[r] *= sf[r];
        }
        float p[4][4];
        #pragma unroll
        for (int kt = 0; kt < 4; ++kt) {
            #pragma unroll
            for (int r = 0; r < 4; ++r) {
                const float pv = exp2f(sacc[kt][r] - m_r[r]);
                p[kt][r] = pv;
                l_r[r] += pv;               // lane-partial; reduced at the end
            }
        }
        #pragma unroll
        for (int ct = 0; ct < 4; ++ct) {
            #pragma unroll
            for (int r = 0; r < 4; ++r) oacc[ct][r] *= sf[r];
        }

        // ---- P -> wave-private LDS (bf16), read back as PV A-fragments ----
        #pragma unroll
        for (int kt = 0; kt < 4; ++kt) {
            #pragma unroll
            for (int r = 0; r < 4; ++r)
                Plds[wave][(4 * g + r) * 72 + kt * 16 + lr] = f2bf(p[kt][r]);
        }
        // (same-wave RAW on LDS: compiler inserts lgkmcnt waits; no barrier needed)
        #pragma unroll
        for (int ks = 0; ks < 2; ++ks) {
            s16x8 pf = *(const s16x8*)(&Plds[wave][lr * 72 + ks * 32 + g * 8]);
            #pragma unroll
            for (int ct = 0; ct < 4; ++ct) {
                const int c  = ct * 16 + lr;
                const int sb = (ks * 4 + g) ^ (c & 7);
                s16x8 vf = *(const s16x8*)(Vlds + c * 64 + sb * 8);
                oacc[ct] = __builtin_amdgcn_mfma_f32_16x16x32_bf16(pf, vf, oacc[ct], 0, 0, 0);
            }
        }
        __syncthreads();   // protect K/V LDS before next stage
    }

    // ---- finalize: reduce l across the 16-lane group, normalize, store ----
    #pragma unroll
    for (int mask = 1; mask < 16; mask <<= 1) {
        #pragma unroll
        for (int r = 0; r < 4; ++r) l_r[r] += __shfl_xor(l_r[r], mask, 64);
    }
    uint16_t* Ob = Og + (size_t)bh * S_ * 64;
    #pragma unroll
    for (int r = 0; r < 4; ++r) {
        const float inv = 1.0f / l_r[r];
        const int t = q0 + 4 * g + r;
        #pragma unroll
        for (int ct = 0; ct < 4; ++ct)
            Ob[(size_t)t * 64 + ct * 16 + lr] = f2bf(oacc[ct][r] * inv);
    }
}

// ---------------------------------------------------------------------------
// Kernel 3: output projection + residual. grid=576, block=64.
// The reference's reshape scramble: out channel c' = h*16 + c/4 at spatial
// hw' = (c&3)*2304 + s  ==  element [bh][t=s][c=4m+r] of the attn buffer.
// ---------------------------------------------------------------------------
__global__ __launch_bounds__(64) void out_proj(
    const uint16_t* __restrict__ A2, const float* __restrict__ x,
    const float* __restrict__ Wo, const float* __restrict__ bo,
    float* __restrict__ out)
{
    const int pix = blockIdx.x * 64 + threadIdx.x;
    const int b  = pix / HW_;
    const int hw = pix % HW_;
    const int r  = hw / S_;      // uniform per block (2304 % 64 == 0)
    const int s  = hw % S_;

    float a[64];
    #pragma unroll
    for (int h = 0; h < 4; ++h) {
        const uint16_t* Ab = A2 + (((size_t)(b * 4 + h)) * S_ + s) * 64 + r;
        #pragma unroll
        for (int m = 0; m < 16; ++m)
            a[h * 16 + m] = bf2f(Ab[4 * m]);
    }

    const size_t xoff = (size_t)b * C_ * HW_ + hw;
    #pragma unroll 2
    for (int o = 0; o < 64; ++o) {
        float acc = bo[o] + x[xoff + (size_t)o * HW_];
        #pragma unroll
        for (int c = 0; c < 64; ++c) acc = fmaf(Wo[o * 64 + c], a[c], acc);
        out[xoff + (size_t)o * HW_] = acc;
    }
}

// ---------------------------------------------------------------------------
extern "C" void kernel_launch(void* const* d_in, const int* in_sizes, int n_in,
                              void* d_out, int out_size, void* d_ws, size_t ws_size,
                              hipStream_t stream) {
    const float* x  = (const float*)d_in[0];
    const float* Wq = (const float*)d_in[1];
    const float* Wk = (const float*)d_in[2];
    const float* Wv = (const float*)d_in[3];
    const float* Wo = (const float*)d_in[4];
    const float* bq = (const float*)d_in[5];
    const float* bk = (const float*)d_in[6];
    const float* bv = (const float*)d_in[7];
    const float* bo = (const float*)d_in[8];
    float* out = (float*)d_out;

    const size_t n = (size_t)NBH * S_ * 64;   // 2,359,296 elems per buffer
    uint16_t* Q  = (uint16_t*)d_ws;
    uint16_t* K  = Q + n;
    uint16_t* V  = K + n;
    uint16_t* A2 = V + n;                     // total 4*n*2B = 18.9 MB

    qkv_proj<<<dim3(576, 3), 64, 0, stream>>>(x, Wq, Wk, Wv, bq, bk, bv, Q, K, V);
    attn<<<dim3(36, 16), 256, 0, stream>>>(Q, K, V, A2);
    out_proj<<<576, 64, 0, stream>>>(A2, x, Wo, bo, out);
}

// Round 2
// 222.020 us; speedup vs baseline: 1.0384x; 1.0384x over previous
//
#include <hip/hip_runtime.h>
#include <stdint.h>

#define HW_  9216
#define HS_  4
#define S_   2304
#define NBH  16
// 0.5 (softmax scale = 1/sqrt(head_size=4)) * log2(e), folded into Q at projection time
#define SCALE_LOG2E 0.72134752044448169136f

using f32x4 = __attribute__((ext_vector_type(4))) float;
using u32x4 = __attribute__((ext_vector_type(4))) uint32_t;
using s16x8 = __attribute__((ext_vector_type(8))) short;   // 8 bf16 in 4 VGPRs

__device__ __forceinline__ uint16_t f2bf(float f) {
    uint32_t u = __builtin_bit_cast(uint32_t, f);
    uint32_t r = u + 0x7FFFu + ((u >> 16) & 1u);   // RNE
    return (uint16_t)(r >> 16);
}
__device__ __forceinline__ float bf2f(uint16_t h) {
    uint32_t u = ((uint32_t)h) << 16;
    return __builtin_bit_cast(float, u);
}

// ---------------------------------------------------------------------------
// Kernel 1: q/k/v projection (1x1 conv). grid=(576,3), block=64.
// mode 0: Q, scaled by 0.5*log2e, row-major [bh][s][c] bf16
// mode 1: K,                      row-major [bh][s][c] bf16
// mode 2: V, transposed           [bh][c][s] bf16
// ---------------------------------------------------------------------------
__global__ __launch_bounds__(64) void qkv_proj(
    const float* __restrict__ x,
    const float* __restrict__ Wq, const float* __restrict__ Wk, const float* __restrict__ Wv,
    const float* __restrict__ bq, const float* __restrict__ bk, const float* __restrict__ bv,
    uint16_t* __restrict__ Qo, uint16_t* __restrict__ Ko, uint16_t* __restrict__ Vo)
{
    const int mode = blockIdx.y;
    const float* W    = (mode == 0) ? Wq : (mode == 1) ? Wk : Wv;
    const float* bias = (mode == 0) ? bq : (mode == 1) ? bk : bv;

    const int pix = blockIdx.x * 64 + threadIdx.x;
    const int b  = pix / HW_;
    const int hw = pix % HW_;
    const int h  = hw / S_;
    const int s  = hw % S_;
    const int bh = b * HS_ + h;

    float xv[64];
    #pragma unroll
    for (int c = 0; c < 64; ++c)
        xv[c] = x[(size_t)(b * 64 + c) * HW_ + hw];   // coalesced across lanes

    if (mode == 2) {
        #pragma unroll 4
        for (int o = 0; o < 64; ++o) {
            float acc = bias[o];
            #pragma unroll
            for (int c = 0; c < 64; ++c) acc = fmaf(W[o * 64 + c], xv[c], acc);
            Vo[((size_t)bh * 64 + o) * S_ + s] = f2bf(acc);
        }
    } else {
        const float scale = (mode == 0) ? SCALE_LOG2E : 1.0f;
        uint16_t* dst = ((mode == 0) ? Qo : Ko) + ((size_t)bh * S_ + s) * 64;
        #pragma unroll 4
        for (int op = 0; op < 32; ++op) {
            const int o = op * 2;
            float a0 = bias[o], a1 = bias[o + 1];
            #pragma unroll
            for (int c = 0; c < 64; ++c) {
                a0 = fmaf(W[o * 64 + c],       xv[c], a0);
                a1 = fmaf(W[(o + 1) * 64 + c], xv[c], a1);
            }
            a0 *= scale; a1 *= scale;
            uint32_t pk = (uint32_t)f2bf(a0) | ((uint32_t)f2bf(a1) << 16);
            ((uint32_t*)dst)[op] = pk;
        }
    }
}

// ---------------------------------------------------------------------------
// Kernel 2: flash attention, barrier-free. grid=1152, block=64 (1 wave, 32 q).
// K/V fragments are loaded straight from global (L2-resident per XCD thanks to
// the bh<->XCD swizzle: 2 bh per XCD = 2.4MB < 4MB L2). Single-buffered
// register prefetch: next-j K loads issue right after QK^T consumes them,
// next-j V loads right after PV — latency hides under softmax/MFMA, no
// barriers anywhere. A/B fragments share the same (lane,elem)->k map, so MFMA
// contraction is correct for any HW k-permutation; only the verified C/D
// layout (col=lane&15, row=(lane>>4)*4+reg) is relied on.
// Output goes through an LDS transpose straight into the reference's
// post-reshape scrambled layout [b][c'][hw'], c'=h*16+c/4, hw'=(c%4)*2304+t.
// ---------------------------------------------------------------------------
__global__ __launch_bounds__(64) void attn(
    const uint16_t* __restrict__ Qg, const uint16_t* __restrict__ Kg,
    const uint16_t* __restrict__ Vg, uint16_t* __restrict__ A2)
{
    const int blk = blockIdx.x;          // 1152 = 8 xcd * (2 bh * 72 qb)
    const int xcd = blk & 7;
    const int i   = blk >> 3;            // 0..143
    const int bh  = xcd * 2 + (i & 1);
    const int qb  = i >> 1;              // 0..71
    const int q0  = qb * 32;
    const int b   = bh >> 2;
    const int h   = bh & 3;

    const int lane = threadIdx.x;
    const int g    = lane >> 4;          // 0..3
    const int lr   = lane & 15;          // 0..15

    __shared__ alignas(16) uint16_t Plds[32 * 72];   // P bounce, stride 72 (16B-aligned rows)
    __shared__ float Obuf[32 * 68];                  // output transpose, stride 68 (conflict-free)

    const uint16_t* Qb = Qg + (size_t)bh * S_ * 64;
    const uint16_t* Kb = Kg + (size_t)bh * S_ * 64;
    const uint16_t* Vb = Vg + (size_t)bh * 64 * S_;

    // Q fragments: 2 row-tiles x 2 k-halves, register-resident
    s16x8 qf[2][2];
    #pragma unroll
    for (int qt = 0; qt < 2; ++qt)
        #pragma unroll
        for (int ks = 0; ks < 2; ++ks)
            qf[qt][ks] = *(const s16x8*)(Qb + (size_t)(q0 + qt * 16 + lr) * 64 + ks * 32 + g * 8);

    f32x4 oacc[2][4];
    float m_r[2][4], l_r[2][4];
    #pragma unroll
    for (int qt = 0; qt < 2; ++qt) {
        #pragma unroll
        for (int ct = 0; ct < 4; ++ct) oacc[qt][ct] = (f32x4){0.f, 0.f, 0.f, 0.f};
        #pragma unroll
        for (int r = 0; r < 4; ++r) { m_r[qt][r] = -1e30f; l_r[qt][r] = 0.f; }
    }

    // prologue: load K/V fragments for j=0
    s16x8 kf[2][4], vf[2][4];
    #pragma unroll
    for (int ks = 0; ks < 2; ++ks)
        #pragma unroll
        for (int kt = 0; kt < 4; ++kt)
            kf[ks][kt] = *(const s16x8*)(Kb + (size_t)(kt * 16 + lr) * 64 + ks * 32 + g * 8);
    #pragma unroll
    for (int ks = 0; ks < 2; ++ks)
        #pragma unroll
        for (int ct = 0; ct < 4; ++ct)
            vf[ks][ct] = *(const s16x8*)(Vb + (size_t)(ct * 16 + lr) * S_ + ks * 32 + g * 8);

    for (int j = 0; j < 36; ++j) {
        // ---- S = Q K^T (logits pre-scaled into exp2 domain) ----
        f32x4 sacc[2][4];
        #pragma unroll
        for (int qt = 0; qt < 2; ++qt)
            #pragma unroll
            for (int kt = 0; kt < 4; ++kt) sacc[qt][kt] = (f32x4){0.f, 0.f, 0.f, 0.f};
        #pragma unroll
        for (int ks = 0; ks < 2; ++ks)
            #pragma unroll
            for (int kt = 0; kt < 4; ++kt)
                #pragma unroll
                for (int qt = 0; qt < 2; ++qt)
                    sacc[qt][kt] = __builtin_amdgcn_mfma_f32_16x16x32_bf16(
                        qf[qt][ks], kf[ks][kt], sacc[qt][kt], 0, 0, 0);

        // prefetch next-j K fragments (WAR on kf; wait handled by compiler)
        if (j < 35) {
            const uint16_t* Kn = Kb + (size_t)(j + 1) * 64 * 64;
            #pragma unroll
            for (int ks = 0; ks < 2; ++ks)
                #pragma unroll
                for (int kt = 0; kt < 4; ++kt)
                    kf[ks][kt] = *(const s16x8*)(Kn + (size_t)(kt * 16 + lr) * 64 + ks * 32 + g * 8);
        }

        // ---- online softmax (rows qt*16+4g+r, cols kt*16+lr) ----
        #pragma unroll
        for (int qt = 0; qt < 2; ++qt) {
            float tm[4];
            #pragma unroll
            for (int r = 0; r < 4; ++r)
                tm[r] = fmaxf(fmaxf(sacc[qt][0][r], sacc[qt][1][r]),
                              fmaxf(sacc[qt][2][r], sacc[qt][3][r]));
            #pragma unroll
            for (int mask = 1; mask < 16; mask <<= 1) {
                #pragma unroll
                for (int r = 0; r < 4; ++r)
                    tm[r] = fmaxf(tm[r], __shfl_xor(tm[r], mask, 64));
            }
            #pragma unroll
            for (int r = 0; r < 4; ++r) {
                const float mn = fmaxf(m_r[qt][r], tm[r]);
                const float sf = exp2f(m_r[qt][r] - mn);
                m_r[qt][r] = mn;
                l_r[qt][r] *= sf;
                #pragma unroll
                for (int ct = 0; ct < 4; ++ct) oacc[qt][ct][r] *= sf;
            }
            #pragma unroll
            for (int kt = 0; kt < 4; ++kt) {
                #pragma unroll
                for (int r = 0; r < 4; ++r) {
                    const float pv = exp2f(sacc[qt][kt][r] - m_r[qt][r]);
                    l_r[qt][r] += pv;
                    Plds[(qt * 16 + 4 * g + r) * 72 + kt * 16 + lr] = f2bf(pv);
                }
            }
        }

        // ---- PV: read P back as A-fragments, V as B-fragments ----
        #pragma unroll
        for (int ks = 0; ks < 2; ++ks) {
            #pragma unroll
            for (int qt = 0; qt < 2; ++qt) {
                s16x8 pf = *(const s16x8*)(&Plds[(qt * 16 + lr) * 72 + ks * 32 + g * 8]);
                #pragma unroll
                for (int ct = 0; ct < 4; ++ct)
                    oacc[qt][ct] = __builtin_amdgcn_mfma_f32_16x16x32_bf16(
                        pf, vf[ks][ct], oacc[qt][ct], 0, 0, 0);
            }
        }

        // prefetch next-j V fragments
        if (j < 35) {
            const uint16_t* Vn = Vb + (size_t)(j + 1) * 64;
            #pragma unroll
            for (int ks = 0; ks < 2; ++ks)
                #pragma unroll
                for (int ct = 0; ct < 4; ++ct)
                    vf[ks][ct] = *(const s16x8*)(Vn + (size_t)(ct * 16 + lr) * S_ + ks * 32 + g * 8);
        }
    }

    // ---- finalize: reduce l over the 16-lane group, normalize into Obuf ----
    #pragma unroll
    for (int mask = 1; mask < 16; mask <<= 1) {
        #pragma unroll
        for (int qt = 0; qt < 2; ++qt)
            #pragma unroll
            for (int r = 0; r < 4; ++r)
                l_r[qt][r] += __shfl_xor(l_r[qt][r], mask, 64);
    }
    #pragma unroll
    for (int qt = 0; qt < 2; ++qt) {
        #pragma unroll
        for (int r = 0; r < 4; ++r) {
            const float inv = 1.0f / l_r[qt][r];
            const int tl = qt * 16 + 4 * g + r;
            #pragma unroll
            for (int ct = 0; ct < 4; ++ct)
                Obuf[tl * 68 + ct * 16 + lr] = oacc[qt][ct][r] * inv;
        }
    }
    // single wave: compiler orders LDS RAW with lgkmcnt; no barrier needed.
    // ---- write scrambled layout: lane owns channel c, 32 consecutive t ----
    const int c = lane;
    uint16_t* dst = A2 + ((size_t)(b * 64 + h * 16 + (c >> 2)) * HW_ + (c & 3) * S_ + q0);
    #pragma unroll
    for (int sgm = 0; sgm < 4; ++sgm) {
        uint32_t pk[4];
        #pragma unroll
        for (int e = 0; e < 4; ++e) {
            const int t = sgm * 8 + e * 2;
            pk[e] = (uint32_t)f2bf(Obuf[t * 68 + c]) |
                    ((uint32_t)f2bf(Obuf[(t + 1) * 68 + c]) << 16);
        }
        *(u32x4*)(dst + sgm * 8) = (u32x4){pk[0], pk[1], pk[2], pk[3]};
    }
}

// ---------------------------------------------------------------------------
// Kernel 3: output projection + residual. grid=(576,2), block=64.
// A2 is already in the scrambled channel-major layout -> fully coalesced.
// ---------------------------------------------------------------------------
__global__ __launch_bounds__(64) void out_proj(
    const uint16_t* __restrict__ A2, const float* __restrict__ x,
    const float* __restrict__ Wo, const float* __restrict__ bo,
    float* __restrict__ out)
{
    const int pix = blockIdx.x * 64 + threadIdx.x;
    const int b  = pix / HW_;
    const int hw = pix % HW_;
    const int o0 = blockIdx.y * 32;

    float a[64];
    #pragma unroll
    for (int c = 0; c < 64; ++c)
        a[c] = bf2f(A2[(size_t)(b * 64 + c) * HW_ + hw]);   // coalesced

    const size_t xoff = (size_t)b * 64 * HW_ + hw;
    #pragma unroll 2
    for (int oi = 0; oi < 32; ++oi) {
        const int o = o0 + oi;
        float acc = bo[o] + x[xoff + (size_t)o * HW_];
        #pragma unroll
        for (int c = 0; c < 64; ++c) acc = fmaf(Wo[o * 64 + c], a[c], acc);
        out[xoff + (size_t)o * HW_] = acc;
    }
}

// ---------------------------------------------------------------------------
extern "C" void kernel_launch(void* const* d_in, const int* in_sizes, int n_in,
                              void* d_out, int out_size, void* d_ws, size_t ws_size,
                              hipStream_t stream) {
    const float* x  = (const float*)d_in[0];
    const float* Wq = (const float*)d_in[1];
    const float* Wk = (const float*)d_in[2];
    const float* Wv = (const float*)d_in[3];
    const float* Wo = (const float*)d_in[4];
    const float* bq = (const float*)d_in[5];
    const float* bk = (const float*)d_in[6];
    const float* bv = (const float*)d_in[7];
    const float* bo = (const float*)d_in[8];
    float* out = (float*)d_out;

    const size_t n = (size_t)NBH * S_ * 64;   // 2,359,296 elems per buffer
    uint16_t* Q  = (uint16_t*)d_ws;
    uint16_t* K  = Q + n;
    uint16_t* V  = K + n;
    uint16_t* A2 = V + n;                     // total 4*n*2B = 18.9 MB

    qkv_proj<<<dim3(576, 3), 64, 0, stream>>>(x, Wq, Wk, Wv, bq, bk, bv, Q, K, V);
    attn<<<1152, 64, 0, stream>>>(Q, K, V, A2);
    out_proj<<<dim3(576, 2), 64, 0, stream>>>(A2, x, Wo, bo, out);
}

// Round 3
// 201.762 us; speedup vs baseline: 1.1427x; 1.1004x over previous
//
#include <hip/hip_runtime.h>
#include <stdint.h>

#define HW_  9216
#define S_   2304
#define NBH  16
#define NSPLIT 4
#define JPS  9          // KV tiles per split (36/4)
// 0.5 (softmax scale = 1/sqrt(head_size=4)) * log2(e), folded into Q at projection time
#define SCALE_LOG2E 0.72134752044448169136f

using f32x4 = __attribute__((ext_vector_type(4))) float;
using u32x4 = __attribute__((ext_vector_type(4))) uint32_t;
using s16x8 = __attribute__((ext_vector_type(8))) short;   // 8 bf16 in 4 VGPRs

__device__ __forceinline__ uint16_t f2bf(float f) {
    uint32_t u = __builtin_bit_cast(uint32_t, f);
    uint32_t r = u + 0x7FFFu + ((u >> 16) & 1u);   // RNE
    return (uint16_t)(r >> 16);
}
__device__ __forceinline__ float bf2f(uint16_t h) {
    uint32_t u = ((uint32_t)h) << 16;
    return __builtin_bit_cast(float, u);
}

// ---------------------------------------------------------------------------
// Kernel 1: q/k/v projection (1x1 conv). grid=(576,3,2), block=64.
// z splits the 64 output channels into 2x32 for occupancy (3456 waves).
// mode 0: Q, scaled by 0.5*log2e, row-major [bh][s][c] bf16
// mode 1: K,                      row-major [bh][s][c] bf16
// mode 2: V, transposed           [bh][c][s] bf16
// ---------------------------------------------------------------------------
__global__ __launch_bounds__(64) void qkv_proj(
    const float* __restrict__ x,
    const float* __restrict__ Wq, const float* __restrict__ Wk, const float* __restrict__ Wv,
    const float* __restrict__ bq, const float* __restrict__ bk, const float* __restrict__ bv,
    uint16_t* __restrict__ Qo, uint16_t* __restrict__ Ko, uint16_t* __restrict__ Vo)
{
    const int mode = blockIdx.y;
    const int o0   = blockIdx.z * 32;
    const float* W    = (mode == 0) ? Wq : (mode == 1) ? Wk : Wv;
    const float* bias = (mode == 0) ? bq : (mode == 1) ? bk : bv;

    const int pix = blockIdx.x * 64 + threadIdx.x;
    const int b  = pix / HW_;
    const int hw = pix % HW_;
    const int h  = hw / S_;
    const int s  = hw % S_;
    const int bh = b * 4 + h;

    float xv[64];
    #pragma unroll
    for (int c = 0; c < 64; ++c)
        xv[c] = x[(size_t)(b * 64 + c) * HW_ + hw];   // coalesced across lanes

    if (mode == 2) {
        #pragma unroll 4
        for (int oi = 0; oi < 32; ++oi) {
            const int o = o0 + oi;
            float acc = bias[o];
            #pragma unroll
            for (int c = 0; c < 64; ++c) acc = fmaf(W[o * 64 + c], xv[c], acc);
            Vo[((size_t)bh * 64 + o) * S_ + s] = f2bf(acc);
        }
    } else {
        const float scale = (mode == 0) ? SCALE_LOG2E : 1.0f;
        uint16_t* dst = ((mode == 0) ? Qo : Ko) + ((size_t)bh * S_ + s) * 64;
        #pragma unroll 4
        for (int op = 0; op < 16; ++op) {
            const int o = o0 + op * 2;
            float a0 = bias[o], a1 = bias[o + 1];
            #pragma unroll
            for (int c = 0; c < 64; ++c) {
                a0 = fmaf(W[o * 64 + c],       xv[c], a0);
                a1 = fmaf(W[(o + 1) * 64 + c], xv[c], a1);
            }
            a0 *= scale; a1 *= scale;
            uint32_t pk = (uint32_t)f2bf(a0) | ((uint32_t)f2bf(a1) << 16);
            ((uint32_t*)dst)[o0 / 2 + op] = pk;
        }
    }
}

// ---------------------------------------------------------------------------
// Kernel 2: flash attention, no-max softmax, split-KV x4. grid=4608, block=64.
// Softmax uses a FIXED max of 0 (logits bounded; f32/exp2 has huge headroom):
// P = exp2(s'), l = sum P. No running max, no rescale, no cross-lane ops in
// the loop. Each wave handles 32 queries x 9 KV tiles and emits UNNORMALIZED
// bf16 partial-O (scrambled output layout) + f32 partial-l; out_proj merges.
// K/V fragments load straight from L2 (bh<->XCD swizzle keeps slices
// resident); register prefetch one tile ahead; no barriers anywhere.
// C/D layout (col=lane&15, row=(lane>>4)*4+reg) per learn_hip m89.
// ---------------------------------------------------------------------------
__global__ __launch_bounds__(64) void attn(
    const uint16_t* __restrict__ Qg, const uint16_t* __restrict__ Kg,
    const uint16_t* __restrict__ Vg, uint16_t* __restrict__ Op,
    float* __restrict__ Lp)
{
    const int blk = blockIdx.x;          // 4608 = 8 xcd * (2 bh * 4 sp * 72 qb)
    const int xcd = blk & 7;
    const int i   = blk >> 3;            // 0..575
    const int bh  = xcd * 2 + (i & 1);
    const int i2  = i >> 1;              // 0..287
    const int sp  = i2 & 3;              // KV split 0..3
    const int qb  = i2 >> 2;             // 0..71
    const int q0  = qb * 32;
    const int j0  = sp * JPS;
    const int b   = bh >> 2;
    const int h   = bh & 3;

    const int lane = threadIdx.x;
    const int g    = lane >> 4;          // 0..3
    const int lr   = lane & 15;          // 0..15

    // P bounce (u16, stride 72) and output transpose (f32, stride 68) alias:
    // P is live only inside the loop, Obuf only after it.
    __shared__ alignas(16) uint32_t smem[32 * 68];         // 8704 B
    uint16_t* Plds = (uint16_t*)smem;
    float*    Obuf = (float*)smem;

    const uint16_t* Qb = Qg + (size_t)bh * S_ * 64;
    const uint16_t* Kb = Kg + (size_t)bh * S_ * 64;
    const uint16_t* Vb = Vg + (size_t)bh * 64 * S_;

    // Q fragments: 2 row-tiles x 2 k-halves, register-resident
    s16x8 qf[2][2];
    #pragma unroll
    for (int qt = 0; qt < 2; ++qt)
        #pragma unroll
        for (int ks = 0; ks < 2; ++ks)
            qf[qt][ks] = *(const s16x8*)(Qb + (size_t)(q0 + qt * 16 + lr) * 64 + ks * 32 + g * 8);

    f32x4 oacc[2][4];
    float l_r[2][4];
    #pragma unroll
    for (int qt = 0; qt < 2; ++qt) {
        #pragma unroll
        for (int ct = 0; ct < 4; ++ct) oacc[qt][ct] = (f32x4){0.f, 0.f, 0.f, 0.f};
        #pragma unroll
        for (int r = 0; r < 4; ++r) l_r[qt][r] = 0.f;
    }

    // prologue: K/V fragments for tile j0
    s16x8 kf[2][4], vf[2][4];
    #pragma unroll
    for (int ks = 0; ks < 2; ++ks)
        #pragma unroll
        for (int kt = 0; kt < 4; ++kt)
            kf[ks][kt] = *(const s16x8*)(Kb + (size_t)(j0 * 64 + kt * 16 + lr) * 64 + ks * 32 + g * 8);
    #pragma unroll
    for (int ks = 0; ks < 2; ++ks)
        #pragma unroll
        for (int ct = 0; ct < 4; ++ct)
            vf[ks][ct] = *(const s16x8*)(Vb + (size_t)(ct * 16 + lr) * S_ + j0 * 64 + ks * 32 + g * 8);

    for (int j = j0; j < j0 + JPS; ++j) {
        // ---- S = Q K^T (logits pre-scaled into exp2 domain) ----
        f32x4 sacc[2][4];
        #pragma unroll
        for (int qt = 0; qt < 2; ++qt)
            #pragma unroll
            for (int kt = 0; kt < 4; ++kt) sacc[qt][kt] = (f32x4){0.f, 0.f, 0.f, 0.f};
        #pragma unroll
        for (int ks = 0; ks < 2; ++ks)
            #pragma unroll
            for (int kt = 0; kt < 4; ++kt)
                #pragma unroll
                for (int qt = 0; qt < 2; ++qt)
                    sacc[qt][kt] = __builtin_amdgcn_mfma_f32_16x16x32_bf16(
                        qf[qt][ks], kf[ks][kt], sacc[qt][kt], 0, 0, 0);

        // prefetch next-tile K fragments
        if (j + 1 < j0 + JPS) {
            const uint16_t* Kn = Kb + (size_t)(j + 1) * 64 * 64;
            #pragma unroll
            for (int ks = 0; ks < 2; ++ks)
                #pragma unroll
                for (int kt = 0; kt < 4; ++kt)
                    kf[ks][kt] = *(const s16x8*)(Kn + (size_t)(kt * 16 + lr) * 64 + ks * 32 + g * 8);
        }

        // ---- P = exp2(S), lane-partial l, bounce P to LDS as bf16 ----
        #pragma unroll
        for (int qt = 0; qt < 2; ++qt)
            #pragma unroll
            for (int kt = 0; kt < 4; ++kt)
                #pragma unroll
                for (int r = 0; r < 4; ++r) {
                    const float pv = __builtin_amdgcn_exp2f(sacc[qt][kt][r]);
                    l_r[qt][r] += pv;
                    Plds[(qt * 16 + 4 * g + r) * 72 + kt * 16 + lr] = f2bf(pv);
                }

        // ---- PV: P back as A-fragments, V as B-fragments ----
        #pragma unroll
        for (int ks = 0; ks < 2; ++ks) {
            #pragma unroll
            for (int qt = 0; qt < 2; ++qt) {
                s16x8 pf = *(const s16x8*)(&Plds[(qt * 16 + lr) * 72 + ks * 32 + g * 8]);
                #pragma unroll
                for (int ct = 0; ct < 4; ++ct)
                    oacc[qt][ct] = __builtin_amdgcn_mfma_f32_16x16x32_bf16(
                        pf, vf[ks][ct], oacc[qt][ct], 0, 0, 0);
            }
        }

        // prefetch next-tile V fragments
        if (j + 1 < j0 + JPS) {
            const uint16_t* Vn = Vb + (size_t)(j + 1) * 64;
            #pragma unroll
            for (int ks = 0; ks < 2; ++ks)
                #pragma unroll
                for (int ct = 0; ct < 4; ++ct)
                    vf[ks][ct] = *(const s16x8*)(Vn + (size_t)(ct * 16 + lr) * S_ + ks * 32 + g * 8);
        }
    }

    // ---- reduce l across the 16-lane group (once) ----
    #pragma unroll
    for (int mask = 1; mask < 16; mask <<= 1) {
        #pragma unroll
        for (int qt = 0; qt < 2; ++qt)
            #pragma unroll
            for (int r = 0; r < 4; ++r)
                l_r[qt][r] += __shfl_xor(l_r[qt][r], mask, 64);
    }

    // ---- transpose unnormalized O through LDS ----
    #pragma unroll
    for (int qt = 0; qt < 2; ++qt)
        #pragma unroll
        for (int r = 0; r < 4; ++r) {
            const int tl = qt * 16 + 4 * g + r;
            #pragma unroll
            for (int ct = 0; ct < 4; ++ct)
                Obuf[tl * 68 + ct * 16 + lr] = oacc[qt][ct][r];
        }
    // single wave: compiler orders LDS RAW via lgkmcnt; no barrier needed.

    // ---- write scrambled-layout bf16 partial: lane owns channel c ----
    const int c = lane;
    uint16_t* dst = Op + (size_t)sp * ((size_t)NBH * S_ * 64)
                  + ((size_t)(b * 64 + h * 16 + (c >> 2)) * HW_ + (c & 3) * S_ + q0);
    #pragma unroll
    for (int sgm = 0; sgm < 4; ++sgm) {
        uint32_t pk[4];
        #pragma unroll
        for (int e = 0; e < 4; ++e) {
            const int t = sgm * 8 + e * 2;
            pk[e] = (uint32_t)f2bf(Obuf[t * 68 + c]) |
                    ((uint32_t)f2bf(Obuf[(t + 1) * 68 + c]) << 16);
        }
        *(u32x4*)(dst + sgm * 8) = (u32x4){pk[0], pk[1], pk[2], pk[3]};
    }

    // ---- write partial l (4 lanes x 8 values) ----
    if (lr == 0) {
        #pragma unroll
        for (int qt = 0; qt < 2; ++qt)
            #pragma unroll
            for (int r = 0; r < 4; ++r)
                Lp[((size_t)sp * NBH + bh) * S_ + q0 + qt * 16 + 4 * g + r] = l_r[qt][r];
    }
}

// ---------------------------------------------------------------------------
// Kernel 3: merge splits + output projection + residual. grid=(576,2), block=64.
// a[c'] = (sum_s O_s[c'])/(sum_s l_s[head(c')]); partials are coalesced.
// ---------------------------------------------------------------------------
__global__ __launch_bounds__(64) void out_proj(
    const uint16_t* __restrict__ Op, const float* __restrict__ Lp,
    const float* __restrict__ x,
    const float* __restrict__ Wo, const float* __restrict__ bo,
    float* __restrict__ out)
{
    const int pix = blockIdx.x * 64 + threadIdx.x;
    const int b  = pix / HW_;
    const int hw = pix % HW_;
    const int t  = hw % S_;
    const int o0 = blockIdx.y * 32;

    float invl[4];
    #pragma unroll
    for (int h = 0; h < 4; ++h) {
        float sl = 0.f;
        #pragma unroll
        for (int sp = 0; sp < NSPLIT; ++sp)
            sl += Lp[((size_t)sp * NBH + b * 4 + h) * S_ + t];
        invl[h] = 1.0f / sl;
    }

    const size_t npart = (size_t)NBH * S_ * 64;
    float a[64];
    #pragma unroll
    for (int c = 0; c < 64; ++c) {
        float v = 0.f;
        #pragma unroll
        for (int sp = 0; sp < NSPLIT; ++sp)
            v += bf2f(Op[(size_t)sp * npart + (size_t)(b * 64 + c) * HW_ + hw]);
        a[c] = v * invl[c >> 4];
    }

    const size_t xoff = (size_t)b * 64 * HW_ + hw;
    #pragma unroll 2
    for (int oi = 0; oi < 32; ++oi) {
        const int o = o0 + oi;
        float acc = bo[o] + x[xoff + (size_t)o * HW_];
        #pragma unroll
        for (int c = 0; c < 64; ++c) acc = fmaf(Wo[o * 64 + c], a[c], acc);
        out[xoff + (size_t)o * HW_] = acc;
    }
}

// ---------------------------------------------------------------------------
extern "C" void kernel_launch(void* const* d_in, const int* in_sizes, int n_in,
                              void* d_out, int out_size, void* d_ws, size_t ws_size,
                              hipStream_t stream) {
    const float* x  = (const float*)d_in[0];
    const float* Wq = (const float*)d_in[1];
    const float* Wk = (const float*)d_in[2];
    const float* Wv = (const float*)d_in[3];
    const float* Wo = (const float*)d_in[4];
    const float* bq = (const float*)d_in[5];
    const float* bk = (const float*)d_in[6];
    const float* bv = (const float*)d_in[7];
    const float* bo = (const float*)d_in[8];
    float* out = (float*)d_out;

    const size_t n = (size_t)NBH * S_ * 64;   // 2,359,296 elems per buffer
    uint16_t* Q  = (uint16_t*)d_ws;
    uint16_t* K  = Q + n;
    uint16_t* V  = K + n;
    uint16_t* Op = V + n;                     // 4 splits x n bf16
    float*    Lp = (float*)(Op + (size_t)NSPLIT * n);   // 4 x 16 x 2304 f32
    // total ws use: 7n*2B + 147456*4B = 33.6 MB

    qkv_proj<<<dim3(576, 3, 2), 64, 0, stream>>>(x, Wq, Wk, Wv, bq, bk, bv, Q, K, V);
    attn<<<4608, 64, 0, stream>>>(Q, K, V, Op, Lp);
    out_proj<<<dim3(576, 2), 64, 0, stream>>>(Op, Lp, x, Wo, bo, out);
}

// Round 6
// 68.851 us; speedup vs baseline: 3.3486x; 2.9304x over previous
//
#include <hip/hip_runtime.h>
#include <stdint.h>

#define HW_  9216
#define S_   2304
#define NBH  16
#define NSPLIT 3
#define JPS  12         // KV tiles per split (36/3)
#define NPART ((size_t)NBH * S_ * 64)
// 0.5 (softmax scale = 1/sqrt(head_size=4)) * log2(e), folded into Wq/bq
#define SCALE_LOG2E 0.72134752044448169136f

using f32x4 = __attribute__((ext_vector_type(4))) float;
using u32x4 = __attribute__((ext_vector_type(4))) uint32_t;
using u32x2 = __attribute__((ext_vector_type(2))) uint32_t;
using s16x8 = __attribute__((ext_vector_type(8))) short;   // 8 bf16 in 4 VGPRs

typedef const __attribute__((address_space(1))) void gbl_void;
typedef __attribute__((address_space(3))) void lds_void;

__device__ __forceinline__ uint32_t pkbf(float lo, float hi) {
    uint32_t r;
    asm("v_cvt_pk_bf16_f32 %0, %1, %2" : "=v"(r) : "v"(lo), "v"(hi));
    return r;
}
__device__ __forceinline__ float bf2f(uint16_t h) {
    return __builtin_bit_cast(float, (uint32_t)h << 16);
}

// ---------------------------------------------------------------------------
// Kernel 1: fused qkv projection, MFMA. grid=(576,3), block=64 (1 wave, 64 pix).
// W held in 8 register fragments; x-tile transposed into LDS [pix][c] bf16
// with 16B-block XOR swizzle. A/B fragment lane maps identical (validated
// R1-R3): m/n = lane&15, k = ks*32 + (lane>>4)*8 + elem.
//   modes 0/1 (Q,K): D[m=out][n=pix] = mfma(wf, xf)  -> store [s][c]
//   mode  2  (V):    D[m=pix][n=out] = mfma(xf, wf)  -> store [c][s]
// Q (weights+bias) pre-scaled by 0.5*log2e.
// ---------------------------------------------------------------------------
__global__ __launch_bounds__(64) void qkv_proj(
    const float* __restrict__ x,
    const float* __restrict__ Wq, const float* __restrict__ Wk, const float* __restrict__ Wv,
    const float* __restrict__ bq, const float* __restrict__ bk, const float* __restrict__ bv,
    uint16_t* __restrict__ Qo, uint16_t* __restrict__ Ko, uint16_t* __restrict__ Vo)
{
    const int mode = blockIdx.y;
    const float* W    = (mode == 0) ? Wq : (mode == 1) ? Wk : Wv;
    const float* bias = (mode == 0) ? bq : (mode == 1) ? bk : bv;
    const float ws = (mode == 0) ? SCALE_LOG2E : 1.0f;

    const int pix0 = blockIdx.x * 64;
    const int b   = pix0 / HW_;
    const int hw0 = pix0 % HW_;
    const int h   = hw0 / S_;          // uniform (S_ % 64 == 0)
    const int s0  = hw0 % S_;
    const int bh  = b * 4 + h;

    const int lane = threadIdx.x;
    const int g = lane >> 4, lr = lane & 15;

    __shared__ alignas(16) uint16_t xt[64 * 64];   // [pix][c] bf16, swizzled

    // ---- x tile: lane owns pixel pix0+lane; pack its channel row to LDS ----
    {
        const float* xb = x + (size_t)b * 64 * HW_ + hw0 + lane;
        uint32_t rp[32];
        #pragma unroll
        for (int cc = 0; cc < 32; ++cc)
            rp[cc] = pkbf(xb[(size_t)(2 * cc) * HW_], xb[(size_t)(2 * cc + 1) * HW_]);
        #pragma unroll
        for (int cb = 0; cb < 8; ++cb) {
            u32x4 d = { rp[cb * 4], rp[cb * 4 + 1], rp[cb * 4 + 2], rp[cb * 4 + 3] };
            *(u32x4*)(xt + lane * 64 + 8 * (cb ^ (lane & 7))) = d;
        }
    }
    __syncthreads();   // order cross-lane LDS write -> read (1 wave: ~free)

    // ---- W fragments (scale folded for Q) ----
    s16x8 wf[4][2];
    #pragma unroll
    for (int t4 = 0; t4 < 4; ++t4)
        #pragma unroll
        for (int ks = 0; ks < 2; ++ks) {
            const float* wp = W + (t4 * 16 + lr) * 64 + ks * 32 + g * 8;
            f32x4 w0 = *(const f32x4*)wp;
            f32x4 w1 = *(const f32x4*)(wp + 4);
            u32x4 d = { pkbf(w0[0] * ws, w0[1] * ws), pkbf(w0[2] * ws, w0[3] * ws),
                        pkbf(w1[0] * ws, w1[1] * ws), pkbf(w1[2] * ws, w1[3] * ws) };
            wf[t4][ks] = __builtin_bit_cast(s16x8, d);
        }

    // ---- x fragments from LDS ----
    s16x8 xf[4][2];
    #pragma unroll
    for (int pt = 0; pt < 4; ++pt)
        #pragma unroll
        for (int ks = 0; ks < 2; ++ks) {
            const int pix = pt * 16 + lr;
            xf[pt][ks] = *(const s16x8*)(xt + pix * 64 + 8 * ((ks * 4 + g) ^ (pix & 7)));
        }

    f32x4 acc[4][4];
    if (mode != 2) {
        #pragma unroll
        for (int mt = 0; mt < 4; ++mt) {
            f32x4 bi = *(const f32x4*)(bias + mt * 16 + g * 4);
            bi *= ws;
            #pragma unroll
            for (int nt = 0; nt < 4; ++nt) acc[mt][nt] = bi;
        }
        #pragma unroll
        for (int ks = 0; ks < 2; ++ks)
            #pragma unroll
            for (int mt = 0; mt < 4; ++mt)
                #pragma unroll
                for (int nt = 0; nt < 4; ++nt)
                    acc[mt][nt] = __builtin_amdgcn_mfma_f32_16x16x32_bf16(
                        wf[mt][ks], xf[nt][ks], acc[mt][nt], 0, 0, 0);
        uint16_t* dst = ((mode == 0) ? Qo : Ko) + ((size_t)bh * S_ + s0) * 64;
        #pragma unroll
        for (int mt = 0; mt < 4; ++mt)
            #pragma unroll
            for (int nt = 0; nt < 4; ++nt) {
                uint32_t d0 = pkbf(acc[mt][nt][0], acc[mt][nt][1]);
                uint32_t d1 = pkbf(acc[mt][nt][2], acc[mt][nt][3]);
                const int o = mt * 16 + g * 4;
                *(uint32_t*)(dst + (nt * 16 + lr) * 64 + o)     = d0;
                *(uint32_t*)(dst + (nt * 16 + lr) * 64 + o + 2) = d1;
            }
    } else {
        #pragma unroll
        for (int nt = 0; nt < 4; ++nt) {
            const float bv = bias[nt * 16 + lr];
            #pragma unroll
            for (int mt = 0; mt < 4; ++mt) acc[mt][nt] = (f32x4){bv, bv, bv, bv};
        }
        #pragma unroll
        for (int ks = 0; ks < 2; ++ks)
            #pragma unroll
            for (int mt = 0; mt < 4; ++mt)
                #pragma unroll
                for (int nt = 0; nt < 4; ++nt)
                    acc[mt][nt] = __builtin_amdgcn_mfma_f32_16x16x32_bf16(
                        xf[mt][ks], wf[nt][ks], acc[mt][nt], 0, 0, 0);
        uint16_t* dst = Vo + (size_t)bh * 64 * S_;
        #pragma unroll
        for (int mt = 0; mt < 4; ++mt)
            #pragma unroll
            for (int nt = 0; nt < 4; ++nt) {
                uint32_t d0 = pkbf(acc[mt][nt][0], acc[mt][nt][1]);
                uint32_t d1 = pkbf(acc[mt][nt][2], acc[mt][nt][3]);
                const int o = nt * 16 + lr;
                const int sb = s0 + mt * 16 + g * 4;
                *(uint32_t*)(dst + (size_t)o * S_ + sb)     = d0;
                *(uint32_t*)(dst + (size_t)o * S_ + sb + 2) = d1;
            }
    }
}

// ---------------------------------------------------------------------------
// Kernel 2: flash attention, no-max softmax, split-KV x3. grid=864, block=256.
// SAFETY-FIRST staging this round (R1-proven serialized pattern): single
// K/V LDS buffer; per tile: stage -> vmcnt(0) -> barrier -> compute ->
// barrier. No overlap (re-add later once correctness is re-anchored).
// Stores UNNORMALIZED bf16 partial-O + f32 partial-l; out_proj merges
// a = (sum_sp O_sp) / (sum_sp l_sp).
// ---------------------------------------------------------------------------
__global__ __launch_bounds__(256, 3) void attn(
    const uint16_t* __restrict__ Qg, const uint16_t* __restrict__ Kg,
    const uint16_t* __restrict__ Vg, uint16_t* __restrict__ Op,
    float* __restrict__ Lp)
{
    const int blk = blockIdx.x;          // 864 = 8 xcd * 2 bh * (3 sp * 18 qb)
    const int xcd = blk & 7;
    const int i   = blk >> 3;            // 0..107
    const int bh  = xcd * 2 + (i & 1);
    const int i2  = i >> 1;              // 0..53
    const int sp  = i2 % 3;
    const int qb  = i2 / 3;              // 0..17
    const int j0  = sp * JPS;
    const int b   = bh >> 2;
    const int h   = bh & 3;

    const int tid  = threadIdx.x;
    const int wave = tid >> 6;
    const int lane = tid & 63;
    const int g    = lane >> 4;
    const int lr   = lane & 15;
    const int q0   = qb * 128 + wave * 32;

    __shared__ alignas(16) uint16_t Kl[4096];      // [key][c] swizzled
    __shared__ alignas(16) uint16_t Vl[4096];      // [c][s]   swizzled
    __shared__ alignas(16) uint16_t Pw[4][2304];   // per-wave P (stride 72) / out-bounce (stride 36)
    uint16_t* P = Pw[wave];

    const uint16_t* Qb = Qg + (size_t)bh * S_ * 64;
    const uint16_t* Kb = Kg + (size_t)bh * S_ * 64;
    const uint16_t* Vb = Vg + (size_t)bh * 64 * S_;

    s16x8 qf[2][2];
    #pragma unroll
    for (int qt = 0; qt < 2; ++qt)
        #pragma unroll
        for (int ks = 0; ks < 2; ++ks)
            qf[qt][ks] = *(const s16x8*)(Qb + (size_t)(q0 + qt * 16 + lr) * 64 + ks * 32 + g * 8);

    f32x4 oacc[2][4];
    float l_r[2][4];
    #pragma unroll
    for (int qt = 0; qt < 2; ++qt) {
        #pragma unroll
        for (int ct = 0; ct < 4; ++ct) oacc[qt][ct] = (f32x4){0.f, 0.f, 0.f, 0.f};
        #pragma unroll
        for (int r = 0; r < 4; ++r) l_r[qt][r] = 0.f;
    }

    for (int jj = 0; jj < JPS; ++jj) {
        const int j = j0 + jj;
        // ---- stage K/V tile (serialized; each wave stages its quarter) ----
        #pragma unroll
        for (int call = 0; call < 2; ++call) {
            const int chunk = wave * 128 + call * 64 + lane;   // 16B units
            const int row   = chunk >> 3;
            const int cb    = (chunk & 7) ^ (row & 7);         // pre-swizzled source
            __builtin_amdgcn_global_load_lds(
                (gbl_void*)(Kb + ((size_t)(j * 64 + row) * 64 + cb * 8)),
                (lds_void*)(Kl + (wave * 128 + call * 64) * 8), 16, 0, 0);
            __builtin_amdgcn_global_load_lds(
                (gbl_void*)(Vb + ((size_t)row * S_ + j * 64 + cb * 8)),
                (lds_void*)(Vl + (wave * 128 + call * 64) * 8), 16, 0, 0);
        }
        asm volatile("s_waitcnt vmcnt(0)" ::: "memory");
        __syncthreads();

        // ---- S = Q K^T (logits pre-scaled into exp2 domain) ----
        f32x4 sacc[2][4];
        #pragma unroll
        for (int qt = 0; qt < 2; ++qt)
            #pragma unroll
            for (int kt = 0; kt < 4; ++kt) sacc[qt][kt] = (f32x4){0.f, 0.f, 0.f, 0.f};
        #pragma unroll
        for (int ks = 0; ks < 2; ++ks)
            #pragma unroll
            for (int kt = 0; kt < 4; ++kt) {
                const int key = kt * 16 + lr;
                s16x8 kf = *(const s16x8*)(&Kl[key * 64 + 8 * ((ks * 4 + g) ^ (key & 7))]);
                sacc[0][kt] = __builtin_amdgcn_mfma_f32_16x16x32_bf16(qf[0][ks], kf, sacc[0][kt], 0, 0, 0);
                sacc[1][kt] = __builtin_amdgcn_mfma_f32_16x16x32_bf16(qf[1][ks], kf, sacc[1][kt], 0, 0, 0);
            }

        // ---- P = exp2(S), lane-partial l, P -> wave-private LDS ----
        #pragma unroll
        for (int qt = 0; qt < 2; ++qt)
            #pragma unroll
            for (int kt = 0; kt < 4; ++kt)
                #pragma unroll
                for (int r = 0; r < 4; ++r) {
                    const float pv = __builtin_amdgcn_exp2f(sacc[qt][kt][r]);
                    l_r[qt][r] += pv;
                    P[(qt * 16 + 4 * g + r) * 72 + kt * 16 + lr] = (uint16_t)pkbf(pv, pv);
                }

        // ---- PV ----
        #pragma unroll
        for (int ks = 0; ks < 2; ++ks) {
            s16x8 pf0 = *(const s16x8*)(P + (0 * 16 + lr) * 72 + ks * 32 + g * 8);
            s16x8 pf1 = *(const s16x8*)(P + (1 * 16 + lr) * 72 + ks * 32 + g * 8);
            #pragma unroll
            for (int ct = 0; ct < 4; ++ct) {
                const int c = ct * 16 + lr;
                s16x8 vf = *(const s16x8*)(&Vl[c * 64 + 8 * ((ks * 4 + g) ^ (c & 7))]);
                oacc[0][ct] = __builtin_amdgcn_mfma_f32_16x16x32_bf16(pf0, vf, oacc[0][ct], 0, 0, 0);
                oacc[1][ct] = __builtin_amdgcn_mfma_f32_16x16x32_bf16(pf1, vf, oacc[1][ct], 0, 0, 0);
            }
        }

        __syncthreads();   // all waves done reading Kl/Vl before next stage
    }

    // ---- reduce l over the 16-lane group ----
    #pragma unroll
    for (int mask = 1; mask < 16; mask <<= 1) {
        #pragma unroll
        for (int qt = 0; qt < 2; ++qt)
            #pragma unroll
            for (int r = 0; r < 4; ++r)
                l_r[qt][r] += __shfl_xor(l_r[qt][r], mask, 64);
    }

    // ---- bounce UNNORMALIZED O as [c][t] (stride 36 u16) into own P region ----
    #pragma unroll
    for (int qt = 0; qt < 2; ++qt)
        #pragma unroll
        for (int ct = 0; ct < 4; ++ct) {
            uint32_t d0 = pkbf(oacc[qt][ct][0], oacc[qt][ct][1]);
            uint32_t d1 = pkbf(oacc[qt][ct][2], oacc[qt][ct][3]);
            const int base = (ct * 16 + lr) * 36 + qt * 16 + 4 * g;
            *(uint32_t*)(P + base)     = d0;
            *(uint32_t*)(P + base + 2) = d1;
        }
    __syncthreads();   // order cross-lane bounce write -> read

    // ---- scrambled-layout store: lane owns channel c, 32 consecutive t ----
    const int c = lane;
    u32x2 wv[8];
    #pragma unroll
    for (int e = 0; e < 8; ++e)
        wv[e] = *(const u32x2*)(P + c * 36 + e * 4);
    uint16_t* dst = Op + (size_t)sp * NPART
                  + ((size_t)(b * 64 + h * 16 + (c >> 2)) * HW_ + (c & 3) * S_ + q0);
    #pragma unroll
    for (int s4 = 0; s4 < 4; ++s4) {
        u32x4 d = { wv[2 * s4][0], wv[2 * s4][1], wv[2 * s4 + 1][0], wv[2 * s4 + 1][1] };
        *(u32x4*)(dst + s4 * 8) = d;
    }

    if (lr == 0) {
        #pragma unroll
        for (int qt = 0; qt < 2; ++qt)
            #pragma unroll
            for (int r = 0; r < 4; ++r)
                Lp[((size_t)sp * NBH + bh) * S_ + q0 + qt * 16 + 4 * g + r] = l_r[qt][r];
    }
}

// ---------------------------------------------------------------------------
// Kernel 3: merge splits + output projection + residual, MFMA. grid=576, block=64.
// a[c'] = (sum_sp O_sp[c']) * 1/(sum_sp l_sp[head(c'), t]).
// ---------------------------------------------------------------------------
__global__ __launch_bounds__(64) void out_proj(
    const uint16_t* __restrict__ Op, const float* __restrict__ Lp,
    const float* __restrict__ x,
    const float* __restrict__ Wo, const float* __restrict__ bo,
    float* __restrict__ out)
{
    const int pix0 = blockIdx.x * 64;
    const int b   = pix0 / HW_;
    const int hw0 = pix0 % HW_;
    const int lane = threadIdx.x;
    const int g = lane >> 4, lr = lane & 15;
    const int t = (hw0 % S_) + lane;     // token of own pixel

    __shared__ alignas(16) uint16_t at[64 * 64];   // [pix][c'] bf16, swizzled

    float inv[4];
    #pragma unroll
    for (int hh = 0; hh < 4; ++hh) {
        float sl = 0.f;
        #pragma unroll
        for (int sp2 = 0; sp2 < NSPLIT; ++sp2)
            sl += Lp[((size_t)sp2 * NBH + b * 4 + hh) * S_ + t];
        inv[hh] = 1.0f / sl;
    }

    {
        const size_t base = (size_t)b * 64 * HW_ + hw0 + lane;
        uint32_t rp[32];
        #pragma unroll
        for (int cc = 0; cc < 32; ++cc) {
            float a0 = 0.f, a1 = 0.f;
            #pragma unroll
            for (int sp2 = 0; sp2 < NSPLIT; ++sp2) {
                const size_t o2 = (size_t)sp2 * NPART + base;
                a0 += bf2f(Op[o2 + (size_t)(2 * cc) * HW_]);
                a1 += bf2f(Op[o2 + (size_t)(2 * cc + 1) * HW_]);
            }
            rp[cc] = pkbf(a0 * inv[(2 * cc) >> 4], a1 * inv[(2 * cc + 1) >> 4]);
        }
        #pragma unroll
        for (int cb = 0; cb < 8; ++cb) {
            u32x4 d = { rp[cb * 4], rp[cb * 4 + 1], rp[cb * 4 + 2], rp[cb * 4 + 3] };
            *(u32x4*)(at + lane * 64 + 8 * (cb ^ (lane & 7))) = d;
        }
    }
    __syncthreads();   // order cross-lane LDS write -> read (1 wave: ~free)

    s16x8 wf[4][2];
    #pragma unroll
    for (int t4 = 0; t4 < 4; ++t4)
        #pragma unroll
        for (int ks = 0; ks < 2; ++ks) {
            const float* wp = Wo + (t4 * 16 + lr) * 64 + ks * 32 + g * 8;
            f32x4 w0 = *(const f32x4*)wp;
            f32x4 w1 = *(const f32x4*)(wp + 4);
            u32x4 d = { pkbf(w0[0], w0[1]), pkbf(w0[2], w0[3]),
                        pkbf(w1[0], w1[1]), pkbf(w1[2], w1[3]) };
            wf[t4][ks] = __builtin_bit_cast(s16x8, d);
        }

    s16x8 af[4][2];
    #pragma unroll
    for (int pt = 0; pt < 4; ++pt)
        #pragma unroll
        for (int ks = 0; ks < 2; ++ks) {
            const int pix = pt * 16 + lr;
            af[pt][ks] = *(const s16x8*)(at + pix * 64 + 8 * ((ks * 4 + g) ^ (pix & 7)));
        }

    f32x4 acc[4][4];
    #pragma unroll
    for (int mt = 0; mt < 4; ++mt) {
        f32x4 bi = *(const f32x4*)(bo + mt * 16 + g * 4);
        #pragma unroll
        for (int nt = 0; nt < 4; ++nt) acc[mt][nt] = bi;
    }
    #pragma unroll
    for (int ks = 0; ks < 2; ++ks)
        #pragma unroll
        for (int mt = 0; mt < 4; ++mt)
            #pragma unroll
            for (int nt = 0; nt < 4; ++nt)
                acc[mt][nt] = __builtin_amdgcn_mfma_f32_16x16x32_bf16(
                    wf[mt][ks], af[nt][ks], acc[mt][nt], 0, 0, 0);

    #pragma unroll
    for (int mt = 0; mt < 4; ++mt)
        #pragma unroll
        for (int nt = 0; nt < 4; ++nt) {
            const int o = mt * 16 + g * 4;
            const size_t rowb = ((size_t)(b * 64 + o)) * HW_ + hw0 + nt * 16 + lr;
            #pragma unroll
            for (int r = 0; r < 4; ++r) {
                const size_t a2 = rowb + (size_t)r * HW_;
                out[a2] = acc[mt][nt][r] + x[a2];
            }
        }
}

// ---------------------------------------------------------------------------
extern "C" void kernel_launch(void* const* d_in, const int* in_sizes, int n_in,
                              void* d_out, int out_size, void* d_ws, size_t ws_size,
                              hipStream_t stream) {
    const float* x  = (const float*)d_in[0];
    const float* Wq = (const float*)d_in[1];
    const float* Wk = (const float*)d_in[2];
    const float* Wv = (const float*)d_in[3];
    const float* Wo = (const float*)d_in[4];
    const float* bq = (const float*)d_in[5];
    const float* bk = (const float*)d_in[6];
    const float* bv = (const float*)d_in[7];
    const float* bo = (const float*)d_in[8];
    float* out = (float*)d_out;

    uint16_t* Q  = (uint16_t*)d_ws;
    uint16_t* K  = Q + NPART;
    uint16_t* V  = K + NPART;
    uint16_t* Op = V + NPART;                       // NSPLIT partials
    float*    Lp = (float*)(Op + (size_t)NSPLIT * NPART);

    qkv_proj<<<dim3(576, 3), 64, 0, stream>>>(x, Wq, Wk, Wv, bq, bk, bv, Q, K, V);
    attn<<<864, 256, 0, stream>>>(Q, K, V, Op, Lp);
    out_proj<<<576, 64, 0, stream>>>(Op, Lp, x, Wo, bo, out);
}

// Round 7
// 68.396 us; speedup vs baseline: 3.3709x; 1.0067x over previous
//
#include <hip/hip_runtime.h>
#include <stdint.h>

#define HW_  9216
#define S_   2304
#define NBH  16
#define NSPLIT 4
#define JPS  9          // KV tiles per split (36/4)
#define NPART ((size_t)NBH * S_ * 64)
// 0.5 (softmax scale = 1/sqrt(head_size=4)) * log2(e), folded into Wq/bq
#define SCALE_LOG2E 0.72134752044448169136f

using f32x4 = __attribute__((ext_vector_type(4))) float;
using u32x4 = __attribute__((ext_vector_type(4))) uint32_t;
using u32x2 = __attribute__((ext_vector_type(2))) uint32_t;
using s16x8 = __attribute__((ext_vector_type(8))) short;   // 8 bf16 in 4 VGPRs

typedef const __attribute__((address_space(1))) void gbl_void;
typedef __attribute__((address_space(3))) void lds_void;

__device__ __forceinline__ uint32_t pkbf(float lo, float hi) {
    uint32_t r;
    asm("v_cvt_pk_bf16_f32 %0, %1, %2" : "=v"(r) : "v"(lo), "v"(hi));
    return r;
}
__device__ __forceinline__ float bf2f(uint16_t h) {
    return __builtin_bit_cast(float, (uint32_t)h << 16);
}

// ---------------------------------------------------------------------------
// Kernel 1: fused qkv projection, MFMA. grid=(576,3,2), block=64.
// z splits outputs into 2x32 (occupancy: 3456 waves). W held in 4 register
// fragments; x-tile transposed into LDS [pix][c] bf16 w/ 16B-block XOR
// swizzle. A/B fragment lane maps identical (validated R1-R6).
//   modes 0/1 (Q,K): D[m=out][n=pix] = mfma(wf, xf)  -> store [s][c]
//   mode  2  (V):    D[m=pix][n=out] = mfma(xf, wf)  -> store [c][s]
// Q (weights+bias) pre-scaled by 0.5*log2e.
// ---------------------------------------------------------------------------
__global__ __launch_bounds__(64) void qkv_proj(
    const float* __restrict__ x,
    const float* __restrict__ Wq, const float* __restrict__ Wk, const float* __restrict__ Wv,
    const float* __restrict__ bq, const float* __restrict__ bk, const float* __restrict__ bv,
    uint16_t* __restrict__ Qo, uint16_t* __restrict__ Ko, uint16_t* __restrict__ Vo)
{
    const int mode = blockIdx.y;
    const int o0   = blockIdx.z * 32;
    const float* W    = (mode == 0) ? Wq : (mode == 1) ? Wk : Wv;
    const float* bias = (mode == 0) ? bq : (mode == 1) ? bk : bv;
    const float ws = (mode == 0) ? SCALE_LOG2E : 1.0f;

    const int pix0 = blockIdx.x * 64;
    const int b   = pix0 / HW_;
    const int hw0 = pix0 % HW_;
    const int h   = hw0 / S_;          // uniform (S_ % 64 == 0)
    const int s0  = hw0 % S_;
    const int bh  = b * 4 + h;

    const int lane = threadIdx.x;
    const int g = lane >> 4, lr = lane & 15;

    __shared__ alignas(16) uint16_t xt[64 * 64];   // [pix][c] bf16, swizzled

    // ---- x tile: lane owns pixel pix0+lane; pack its channel row to LDS ----
    {
        const float* xb = x + (size_t)b * 64 * HW_ + hw0 + lane;
        uint32_t rp[32];
        #pragma unroll
        for (int cc = 0; cc < 32; ++cc)
            rp[cc] = pkbf(xb[(size_t)(2 * cc) * HW_], xb[(size_t)(2 * cc + 1) * HW_]);
        #pragma unroll
        for (int cb = 0; cb < 8; ++cb) {
            u32x4 d = { rp[cb * 4], rp[cb * 4 + 1], rp[cb * 4 + 2], rp[cb * 4 + 3] };
            *(u32x4*)(xt + lane * 64 + 8 * (cb ^ (lane & 7))) = d;
        }
    }
    __syncthreads();   // order cross-lane LDS write -> read (1 wave: ~free)

    // ---- W fragments for this block's 32 output rows ----
    s16x8 wf[2][2];
    #pragma unroll
    for (int t2 = 0; t2 < 2; ++t2)
        #pragma unroll
        for (int ks = 0; ks < 2; ++ks) {
            const float* wp = W + (o0 + t2 * 16 + lr) * 64 + ks * 32 + g * 8;
            f32x4 w0 = *(const f32x4*)wp;
            f32x4 w1 = *(const f32x4*)(wp + 4);
            u32x4 d = { pkbf(w0[0] * ws, w0[1] * ws), pkbf(w0[2] * ws, w0[3] * ws),
                        pkbf(w1[0] * ws, w1[1] * ws), pkbf(w1[2] * ws, w1[3] * ws) };
            wf[t2][ks] = __builtin_bit_cast(s16x8, d);
        }

    // ---- x fragments from LDS ----
    s16x8 xf[4][2];
    #pragma unroll
    for (int pt = 0; pt < 4; ++pt)
        #pragma unroll
        for (int ks = 0; ks < 2; ++ks) {
            const int pix = pt * 16 + lr;
            xf[pt][ks] = *(const s16x8*)(xt + pix * 64 + 8 * ((ks * 4 + g) ^ (pix & 7)));
        }

    if (mode != 2) {
        f32x4 acc[2][4];
        #pragma unroll
        for (int mt = 0; mt < 2; ++mt) {
            f32x4 bi = *(const f32x4*)(bias + o0 + mt * 16 + g * 4);
            bi *= ws;
            #pragma unroll
            for (int nt = 0; nt < 4; ++nt) acc[mt][nt] = bi;
        }
        #pragma unroll
        for (int ks = 0; ks < 2; ++ks)
            #pragma unroll
            for (int mt = 0; mt < 2; ++mt)
                #pragma unroll
                for (int nt = 0; nt < 4; ++nt)
                    acc[mt][nt] = __builtin_amdgcn_mfma_f32_16x16x32_bf16(
                        wf[mt][ks], xf[nt][ks], acc[mt][nt], 0, 0, 0);
        uint16_t* dst = ((mode == 0) ? Qo : Ko) + ((size_t)bh * S_ + s0) * 64;
        #pragma unroll
        for (int mt = 0; mt < 2; ++mt)
            #pragma unroll
            for (int nt = 0; nt < 4; ++nt) {
                uint32_t d0 = pkbf(acc[mt][nt][0], acc[mt][nt][1]);
                uint32_t d1 = pkbf(acc[mt][nt][2], acc[mt][nt][3]);
                const int o = o0 + mt * 16 + g * 4;
                *(uint32_t*)(dst + (nt * 16 + lr) * 64 + o)     = d0;
                *(uint32_t*)(dst + (nt * 16 + lr) * 64 + o + 2) = d1;
            }
    } else {
        f32x4 acc[4][2];
        #pragma unroll
        for (int nt = 0; nt < 2; ++nt) {
            const float bv = bias[o0 + nt * 16 + lr];
            #pragma unroll
            for (int mt = 0; mt < 4; ++mt) acc[mt][nt] = (f32x4){bv, bv, bv, bv};
        }
        #pragma unroll
        for (int ks = 0; ks < 2; ++ks)
            #pragma unroll
            for (int mt = 0; mt < 4; ++mt)
                #pragma unroll
                for (int nt = 0; nt < 2; ++nt)
                    acc[mt][nt] = __builtin_amdgcn_mfma_f32_16x16x32_bf16(
                        xf[mt][ks], wf[nt][ks], acc[mt][nt], 0, 0, 0);
        uint16_t* dst = Vo + (size_t)bh * 64 * S_;
        #pragma unroll
        for (int mt = 0; mt < 4; ++mt)
            #pragma unroll
            for (int nt = 0; nt < 2; ++nt) {
                uint32_t d0 = pkbf(acc[mt][nt][0], acc[mt][nt][1]);
                uint32_t d1 = pkbf(acc[mt][nt][2], acc[mt][nt][3]);
                const int o = o0 + nt * 16 + lr;
                const int sb = s0 + mt * 16 + g * 4;
                *(uint32_t*)(dst + (size_t)o * S_ + sb)     = d0;
                *(uint32_t*)(dst + (size_t)o * S_ + sb + 2) = d1;
            }
    }
}

// ---------------------------------------------------------------------------
// Kernel 2: flash attention, no-max softmax, split-KV x4. grid=1152, block=256.
// Body identical to the verified R6 kernel (serialized staging anchor):
// per tile: stage -> vmcnt(0) -> barrier -> compute -> barrier.
// NSPLIT 3->4 raises resident blocks/CU from 3.375 to the LDS cap of 4.
// Stores UNNORMALIZED bf16 partial-O + f32 partial-l; out_proj merges.
// ---------------------------------------------------------------------------
__global__ __launch_bounds__(256, 3) void attn(
    const uint16_t* __restrict__ Qg, const uint16_t* __restrict__ Kg,
    const uint16_t* __restrict__ Vg, uint16_t* __restrict__ Op,
    float* __restrict__ Lp)
{
    const int blk = blockIdx.x;          // 1152 = 8 xcd * 2 bh * (4 sp * 18 qb)
    const int xcd = blk & 7;
    const int i   = blk >> 3;            // 0..143
    const int bh  = xcd * 2 + (i & 1);
    const int i2  = i >> 1;              // 0..71
    const int sp  = i2 & 3;
    const int qb  = i2 >> 2;             // 0..17
    const int j0  = sp * JPS;
    const int b   = bh >> 2;
    const int h   = bh & 3;

    const int tid  = threadIdx.x;
    const int wave = tid >> 6;
    const int lane = tid & 63;
    const int g    = lane >> 4;
    const int lr   = lane & 15;
    const int q0   = qb * 128 + wave * 32;

    __shared__ alignas(16) uint16_t Kl[4096];      // [key][c] swizzled
    __shared__ alignas(16) uint16_t Vl[4096];      // [c][s]   swizzled
    __shared__ alignas(16) uint16_t Pw[4][2304];   // per-wave P (stride 72) / out-bounce (stride 36)
    uint16_t* P = Pw[wave];

    const uint16_t* Qb = Qg + (size_t)bh * S_ * 64;
    const uint16_t* Kb = Kg + (size_t)bh * S_ * 64;
    const uint16_t* Vb = Vg + (size_t)bh * 64 * S_;

    s16x8 qf[2][2];
    #pragma unroll
    for (int qt = 0; qt < 2; ++qt)
        #pragma unroll
        for (int ks = 0; ks < 2; ++ks)
            qf[qt][ks] = *(const s16x8*)(Qb + (size_t)(q0 + qt * 16 + lr) * 64 + ks * 32 + g * 8);

    f32x4 oacc[2][4];
    float l_r[2][4];
    #pragma unroll
    for (int qt = 0; qt < 2; ++qt) {
        #pragma unroll
        for (int ct = 0; ct < 4; ++ct) oacc[qt][ct] = (f32x4){0.f, 0.f, 0.f, 0.f};
        #pragma unroll
        for (int r = 0; r < 4; ++r) l_r[qt][r] = 0.f;
    }

    for (int jj = 0; jj < JPS; ++jj) {
        const int j = j0 + jj;
        // ---- stage K/V tile (serialized; each wave stages its quarter) ----
        #pragma unroll
        for (int call = 0; call < 2; ++call) {
            const int chunk = wave * 128 + call * 64 + lane;   // 16B units
            const int row   = chunk >> 3;
            const int cb    = (chunk & 7) ^ (row & 7);         // pre-swizzled source
            __builtin_amdgcn_global_load_lds(
                (gbl_void*)(Kb + ((size_t)(j * 64 + row) * 64 + cb * 8)),
                (lds_void*)(Kl + (wave * 128 + call * 64) * 8), 16, 0, 0);
            __builtin_amdgcn_global_load_lds(
                (gbl_void*)(Vb + ((size_t)row * S_ + j * 64 + cb * 8)),
                (lds_void*)(Vl + (wave * 128 + call * 64) * 8), 16, 0, 0);
        }
        asm volatile("s_waitcnt vmcnt(0)" ::: "memory");
        __syncthreads();

        // ---- S = Q K^T (logits pre-scaled into exp2 domain) ----
        f32x4 sacc[2][4];
        #pragma unroll
        for (int qt = 0; qt < 2; ++qt)
            #pragma unroll
            for (int kt = 0; kt < 4; ++kt) sacc[qt][kt] = (f32x4){0.f, 0.f, 0.f, 0.f};
        #pragma unroll
        for (int ks = 0; ks < 2; ++ks)
            #pragma unroll
            for (int kt = 0; kt < 4; ++kt) {
                const int key = kt * 16 + lr;
                s16x8 kf = *(const s16x8*)(&Kl[key * 64 + 8 * ((ks * 4 + g) ^ (key & 7))]);
                sacc[0][kt] = __builtin_amdgcn_mfma_f32_16x16x32_bf16(qf[0][ks], kf, sacc[0][kt], 0, 0, 0);
                sacc[1][kt] = __builtin_amdgcn_mfma_f32_16x16x32_bf16(qf[1][ks], kf, sacc[1][kt], 0, 0, 0);
            }

        // ---- P = exp2(S), lane-partial l, P -> wave-private LDS ----
        #pragma unroll
        for (int qt = 0; qt < 2; ++qt)
            #pragma unroll
            for (int kt = 0; kt < 4; ++kt)
                #pragma unroll
                for (int r = 0; r < 4; ++r) {
                    const float pv = __builtin_amdgcn_exp2f(sacc[qt][kt][r]);
                    l_r[qt][r] += pv;
                    P[(qt * 16 + 4 * g + r) * 72 + kt * 16 + lr] = (uint16_t)pkbf(pv, pv);
                }

        // ---- PV ----
        #pragma unroll
        for (int ks = 0; ks < 2; ++ks) {
            s16x8 pf0 = *(const s16x8*)(P + (0 * 16 + lr) * 72 + ks * 32 + g * 8);
            s16x8 pf1 = *(const s16x8*)(P + (1 * 16 + lr) * 72 + ks * 32 + g * 8);
            #pragma unroll
            for (int ct = 0; ct < 4; ++ct) {
                const int c = ct * 16 + lr;
                s16x8 vf = *(const s16x8*)(&Vl[c * 64 + 8 * ((ks * 4 + g) ^ (c & 7))]);
                oacc[0][ct] = __builtin_amdgcn_mfma_f32_16x16x32_bf16(pf0, vf, oacc[0][ct], 0, 0, 0);
                oacc[1][ct] = __builtin_amdgcn_mfma_f32_16x16x32_bf16(pf1, vf, oacc[1][ct], 0, 0, 0);
            }
        }

        __syncthreads();   // all waves done reading Kl/Vl before next stage
    }

    // ---- reduce l over the 16-lane group ----
    #pragma unroll
    for (int mask = 1; mask < 16; mask <<= 1) {
        #pragma unroll
        for (int qt = 0; qt < 2; ++qt)
            #pragma unroll
            for (int r = 0; r < 4; ++r)
                l_r[qt][r] += __shfl_xor(l_r[qt][r], mask, 64);
    }

    // ---- bounce UNNORMALIZED O as [c][t] (stride 36 u16) into own P region ----
    #pragma unroll
    for (int qt = 0; qt < 2; ++qt)
        #pragma unroll
        for (int ct = 0; ct < 4; ++ct) {
            uint32_t d0 = pkbf(oacc[qt][ct][0], oacc[qt][ct][1]);
            uint32_t d1 = pkbf(oacc[qt][ct][2], oacc[qt][ct][3]);
            const int base = (ct * 16 + lr) * 36 + qt * 16 + 4 * g;
            *(uint32_t*)(P + base)     = d0;
            *(uint32_t*)(P + base + 2) = d1;
        }
    __syncthreads();   // order cross-lane bounce write -> read

    // ---- scrambled-layout store: lane owns channel c, 32 consecutive t ----
    const int c = lane;
    u32x2 wv[8];
    #pragma unroll
    for (int e = 0; e < 8; ++e)
        wv[e] = *(const u32x2*)(P + c * 36 + e * 4);
    uint16_t* dst = Op + (size_t)sp * NPART
                  + ((size_t)(b * 64 + h * 16 + (c >> 2)) * HW_ + (c & 3) * S_ + q0);
    #pragma unroll
    for (int s4 = 0; s4 < 4; ++s4) {
        u32x4 d = { wv[2 * s4][0], wv[2 * s4][1], wv[2 * s4 + 1][0], wv[2 * s4 + 1][1] };
        *(u32x4*)(dst + s4 * 8) = d;
    }

    if (lr == 0) {
        #pragma unroll
        for (int qt = 0; qt < 2; ++qt)
            #pragma unroll
            for (int r = 0; r < 4; ++r)
                Lp[((size_t)sp * NBH + bh) * S_ + q0 + qt * 16 + 4 * g + r] = l_r[qt][r];
    }
}

// ---------------------------------------------------------------------------
// Kernel 3: merge splits + output projection + residual, MFMA. grid=(576,2),
// block=64. y splits outputs into 2x32 (1152 waves).
// a[c'] = (sum_sp O_sp[c']) * 1/(sum_sp l_sp[head(c'), t]).
// ---------------------------------------------------------------------------
__global__ __launch_bounds__(64) void out_proj(
    const uint16_t* __restrict__ Op, const float* __restrict__ Lp,
    const float* __restrict__ x,
    const float* __restrict__ Wo, const float* __restrict__ bo,
    float* __restrict__ out)
{
    const int pix0 = blockIdx.x * 64;
    const int o0   = blockIdx.y * 32;
    const int b   = pix0 / HW_;
    const int hw0 = pix0 % HW_;
    const int lane = threadIdx.x;
    const int g = lane >> 4, lr = lane & 15;
    const int t = (hw0 % S_) + lane;     // token of own pixel

    __shared__ alignas(16) uint16_t at[64 * 64];   // [pix][c'] bf16, swizzled

    float inv[4];
    #pragma unroll
    for (int hh = 0; hh < 4; ++hh) {
        float sl = 0.f;
        #pragma unroll
        for (int sp2 = 0; sp2 < NSPLIT; ++sp2)
            sl += Lp[((size_t)sp2 * NBH + b * 4 + hh) * S_ + t];
        inv[hh] = 1.0f / sl;
    }

    {
        const size_t base = (size_t)b * 64 * HW_ + hw0 + lane;
        uint32_t rp[32];
        #pragma unroll
        for (int cc = 0; cc < 32; ++cc) {
            float a0 = 0.f, a1 = 0.f;
            #pragma unroll
            for (int sp2 = 0; sp2 < NSPLIT; ++sp2) {
                const size_t o2 = (size_t)sp2 * NPART + base;
                a0 += bf2f(Op[o2 + (size_t)(2 * cc) * HW_]);
                a1 += bf2f(Op[o2 + (size_t)(2 * cc + 1) * HW_]);
            }
            rp[cc] = pkbf(a0 * inv[(2 * cc) >> 4], a1 * inv[(2 * cc + 1) >> 4]);
        }
        #pragma unroll
        for (int cb = 0; cb < 8; ++cb) {
            u32x4 d = { rp[cb * 4], rp[cb * 4 + 1], rp[cb * 4 + 2], rp[cb * 4 + 3] };
            *(u32x4*)(at + lane * 64 + 8 * (cb ^ (lane & 7))) = d;
        }
    }
    __syncthreads();   // order cross-lane LDS write -> read (1 wave: ~free)

    s16x8 wf[2][2];
    #pragma unroll
    for (int t2 = 0; t2 < 2; ++t2)
        #pragma unroll
        for (int ks = 0; ks < 2; ++ks) {
            const float* wp = Wo + (o0 + t2 * 16 + lr) * 64 + ks * 32 + g * 8;
            f32x4 w0 = *(const f32x4*)wp;
            f32x4 w1 = *(const f32x4*)(wp + 4);
            u32x4 d = { pkbf(w0[0], w0[1]), pkbf(w0[2], w0[3]),
                        pkbf(w1[0], w1[1]), pkbf(w1[2], w1[3]) };
            wf[t2][ks] = __builtin_bit_cast(s16x8, d);
        }

    s16x8 af[4][2];
    #pragma unroll
    for (int pt = 0; pt < 4; ++pt)
        #pragma unroll
        for (int ks = 0; ks < 2; ++ks) {
            const int pix = pt * 16 + lr;
            af[pt][ks] = *(const s16x8*)(at + pix * 64 + 8 * ((ks * 4 + g) ^ (pix & 7)));
        }

    f32x4 acc[2][4];
    #pragma unroll
    for (int mt = 0; mt < 2; ++mt) {
        f32x4 bi = *(const f32x4*)(bo + o0 + mt * 16 + g * 4);
        #pragma unroll
        for (int nt = 0; nt < 4; ++nt) acc[mt][nt] = bi;
    }
    #pragma unroll
    for (int ks = 0; ks < 2; ++ks)
        #pragma unroll
        for (int mt = 0; mt < 2; ++mt)
            #pragma unroll
            for (int nt = 0; nt < 4; ++nt)
                acc[mt][nt] = __builtin_amdgcn_mfma_f32_16x16x32_bf16(
                    wf[mt][ks], af[nt][ks], acc[mt][nt], 0, 0, 0);

    #pragma unroll
    for (int mt = 0; mt < 2; ++mt)
        #pragma unroll
        for (int nt = 0; nt < 4; ++nt) {
            const int o = o0 + mt * 16 + g * 4;
            const size_t rowb = ((size_t)(b * 64 + o)) * HW_ + hw0 + nt * 16 + lr;
            #pragma unroll
            for (int r = 0; r < 4; ++r) {
                const size_t a2 = rowb + (size_t)r * HW_;
                out[a2] = acc[mt][nt][r] + x[a2];
            }
        }
}

// ---------------------------------------------------------------------------
extern "C" void kernel_launch(void* const* d_in, const int* in_sizes, int n_in,
                              void* d_out, int out_size, void* d_ws, size_t ws_size,
                              hipStream_t stream) {
    const float* x  = (const float*)d_in[0];
    const float* Wq = (const float*)d_in[1];
    const float* Wk = (const float*)d_in[2];
    const float* Wv = (const float*)d_in[3];
    const float* Wo = (const float*)d_in[4];
    const float* bq = (const float*)d_in[5];
    const float* bk = (const float*)d_in[6];
    const float* bv = (const float*)d_in[7];
    const float* bo = (const float*)d_in[8];
    float* out = (float*)d_out;

    uint16_t* Q  = (uint16_t*)d_ws;
    uint16_t* K  = Q + NPART;
    uint16_t* V  = K + NPART;
    uint16_t* Op = V + NPART;                       // NSPLIT partials
    float*    Lp = (float*)(Op + (size_t)NSPLIT * NPART);

    qkv_proj<<<dim3(576, 3, 2), 64, 0, stream>>>(x, Wq, Wk, Wv, bq, bk, bv, Q, K, V);
    attn<<<1152, 256, 0, stream>>>(Q, K, V, Op, Lp);
    out_proj<<<dim3(576, 2), 64, 0, stream>>>(Op, Lp, x, Wo, bo, out);
}